// Round 5
// baseline (151.454 us; speedup 1.0000x reference)
//
#include <hip/hip_runtime.h>
#include <math.h>

#define Ec 256
#define Sc 512
#define Bc 2
#define Hc 8
#define Dc 32
#define MAXNORM (1.0f - 1e-5f)
#define NEc (Bc * Sc * Ec)
#define KSPLIT 4
#define NROWS (Bc * Hc * Sc)   // 8192 (b,h,s) rows

__device__ __forceinline__ float fullWaveSum(float v) {
#pragma unroll
  for (int m = 32; m >= 1; m >>= 1) v += __shfl_xor(v, m, 64);
  return v;
}
__device__ __forceinline__ float halfWaveSum(float v) {
#pragma unroll
  for (int m = 16; m >= 1; m >>= 1) v += __shfl_xor(v, m, 64);
  return v;
}
__device__ __forceinline__ float atanh_fast(float z) {   // z in [0, 1)
  return 0.5f * __logf((1.0f + z) / (1.0f - z));
}
__device__ __forceinline__ float tanh_fast(float a) {    // a >= 0
  float e = __expf(-2.0f * a);
  return (1.0f - e) / (1.0f + e);
}

// ---------------------------------------------------------------------------
// Tiled GEMM partial: O[kz] = X[:, kz*64:(kz+1)*64] @ W[:, same]^T
// Tile 32 rows x 64 cols, single K-chunk of 64. grid (M/32, 4*nmat, 4), blk 128
// ---------------------------------------------------------------------------
__global__ __launch_bounds__(128) void gemm_xwt(
    const float* __restrict__ X,
    const float* __restrict__ W0, const float* __restrict__ W1,
    const float* __restrict__ W2,
    float* __restrict__ O0, float* __restrict__ O1, float* __restrict__ O2) {
  const int tid = threadIdx.x;
  const int bx = blockIdx.x;
  const int by = blockIdx.y;
  const int kz = blockIdx.z;
  const int mat = by >> 2;
  const int cb0 = (by & 3) * 64;
  const int rb0 = bx * 32;
  const int kk = kz * 64;
  const float* __restrict__ W = (mat == 0) ? W0 : (mat == 1) ? W1 : W2;
  float* __restrict__ O = ((mat == 0) ? O0 : (mat == 1) ? O1 : O2) + (size_t)kz * NEc;

  __shared__ float Xs[64][36];   // [k][row]
  __shared__ float Ws[64][68];   // [k][col]

  const int f4 = tid & 15;
  const int sub = tid >> 4;
  const int ty = tid >> 4;
  const int tx = tid & 15;

#pragma unroll
  for (int i = 0; i < 4; ++i) {
    int row = sub + i * 8;
    float4 v = *(const float4*)&X[(size_t)(rb0 + row) * Ec + kk + f4 * 4];
    Xs[f4 * 4 + 0][row] = v.x;
    Xs[f4 * 4 + 1][row] = v.y;
    Xs[f4 * 4 + 2][row] = v.z;
    Xs[f4 * 4 + 3][row] = v.w;
  }
#pragma unroll
  for (int i = 0; i < 8; ++i) {
    int col = sub + i * 8;
    float4 v = *(const float4*)&W[(size_t)(cb0 + col) * Ec + kk + f4 * 4];
    Ws[f4 * 4 + 0][col] = v.x;
    Ws[f4 * 4 + 1][col] = v.y;
    Ws[f4 * 4 + 2][col] = v.z;
    Ws[f4 * 4 + 3][col] = v.w;
  }
  __syncthreads();

  float acc[4][4];
#pragma unroll
  for (int i = 0; i < 4; ++i)
#pragma unroll
    for (int j = 0; j < 4; ++j) acc[i][j] = 0.f;

#pragma unroll 8
  for (int k = 0; k < 64; ++k) {
    float4 a = *(const float4*)&Xs[k][ty * 4];
    float4 b = *(const float4*)&Ws[k][tx * 4];
    float av[4] = {a.x, a.y, a.z, a.w};
    float bv[4] = {b.x, b.y, b.z, b.w};
#pragma unroll
    for (int i = 0; i < 4; ++i)
#pragma unroll
      for (int j = 0; j < 4; ++j) acc[i][j] = fmaf(av[i], bv[j], acc[i][j]);
  }
#pragma unroll
  for (int i = 0; i < 4; ++i) {
    float4 o = make_float4(acc[i][0], acc[i][1], acc[i][2], acc[i][3]);
    *(float4*)&O[(size_t)(rb0 + ty * 4 + i) * Ec + cb0 + tx * 4] = o;
  }
}

// ---------------------------------------------------------------------------
// Per-row hyp_linear epilogue for q/k/v (sums the 4 K-split partials)
// ---------------------------------------------------------------------------
__global__ __launch_bounds__(256) void qkv_stats(
    const float* __restrict__ x,
    const float* __restrict__ mxq, const float* __restrict__ mxk,
    const float* __restrict__ mxv,
    const float* __restrict__ bq, const float* __restrict__ bk,
    const float* __restrict__ bv,
    float* __restrict__ qo, float* __restrict__ ko, float* __restrict__ lvo,
    float* __restrict__ qno, float* __restrict__ kno) {
  const int t = threadIdx.x;
  const int row = blockIdx.x;
  const int b = row >> 9;
  const int s = row & (Sc - 1);
  const size_t idx = (size_t)row * Ec + t;
  const float xv = x[idx];
  float mq = 0.f, mk = 0.f, mv = 0.f;
#pragma unroll
  for (int p = 0; p < KSPLIT; ++p) {
    mq += mxq[idx + (size_t)p * NEc];
    mk += mxk[idx + (size_t)p * NEc];
    mv += mxv[idx + (size_t)p * NEc];
  }
  const float bb[3] = {bq[t], bk[t], bv[t]};
  const float mvals[3] = {mq, mk, mv};

  float vals[10] = {xv * xv,
                    mq * mq, mq * bb[0], bb[0] * bb[0],
                    mk * mk, mk * bb[1], bb[1] * bb[1],
                    mv * mv, mv * bb[2], bb[2] * bb[2]};
  __shared__ float red[10][4];
  __shared__ float fin[10];
#pragma unroll
  for (int i = 0; i < 10; ++i) {
    float v = fullWaveSum(vals[i]);
    if ((t & 63) == 0) red[i][t >> 6] = v;
  }
  __syncthreads();
  if (t < 10) fin[t] = red[t][0] + red[t][1] + red[t][2] + red[t][3];
  __syncthreads();

  const float x2 = fin[0];
  const float xn = sqrtf(fmaxf(x2, 1e-15f));
  const float at = atanh_fast(fminf(xn, MAXNORM));  // SC = 1
  const int h = t >> 5;

#pragma unroll
  for (int m = 0; m < 3; ++m) {
    float mx2 = fin[1 + 3 * m];
    float mxb = fin[2 + 3 * m];
    float b2 = fin[3 + 3 * m];
    float mxn = sqrtf(fmaxf(mx2, 1e-15f));
    float scl = tanh_fast((mxn / xn) * at) / mxn;
    float mvv = scl * mvals[m];
    float X2 = scl * scl * mx2;
    float XY = scl * mxb;
    float numc = 1.0f + 2.0f * XY + b2;
    float den = 1.0f + 2.0f * XY + X2 * b2 + 1e-15f;
    float res = (numc * mvv + (1.0f - X2) * bb[m]) / den;
    if (m < 2) {
      res = fminf(res, MAXNORM);                 // elementwise clamp_max
      float s2 = halfWaveSum(res * res);         // per-head ||.||^2 (C=1)
      if (m == 0) {
        qo[idx] = res;
        if ((t & 31) == 0) qno[(b * Hc + h) * Sc + s] = s2;
      } else {
        ko[idx] = res;
        if ((t & 31) == 0) kno[(b * Hc + h) * Sc + s] = s2;
      }
    } else {
      float vn2 = halfWaveSum(res * res);
      float vn = sqrtf(fmaxf(vn2, 1e-15f));
      float f = atanh_fast(fminf(vn, MAXNORM)) / vn;  // logmap0 factor
      lvo[idx] = f * res;
    }
  }
}

// ---------------------------------------------------------------------------
// Fused hyperbolic-distance attention, j-split by 2.
// grid 2048 = b(2)*h(8)*qtile(64 of 8 rows)*jhalf(2); block 256:
//   rs = tid&7  -> q row in tile (1 row/thread)
//   g  = tid>>3 -> 32 j-groups x 8 j each (within this block's 256-j half)
// Score simplification (verified identity): ||(-k)(+)q||^2 = ||q-k||^2/dden,
// dden = 1-2kq+k2*q2  =>  tt = 2||q-k||^2 / (dden*(1-q2)*(1-k2)).
// Loads for K(j) and LV(j) issued together at iteration top; j-loop fully
// unrolled so the compiler can software-pipeline across iterations.
// Writes RAW partial (sum p*lv, sum p) per (row, half); merge kernel finishes.
// ---------------------------------------------------------------------------
__global__ __launch_bounds__(256, 3) void attn_kernel(
    const float* __restrict__ q, const float* __restrict__ k,
    const float* __restrict__ lv, const float* __restrict__ qn,
    const float* __restrict__ kn, const float* __restrict__ hs,
    float* __restrict__ pacc, float* __restrict__ pls) {
  const int tid = threadIdx.x;
  const int rs = tid & 7;
  const int g = tid >> 3;
  const int blk = blockIdx.x;
  const int half = blk & 1;
  const int qt = (blk >> 1) & 63;
  const int h = (blk >> 7) & 7;
  const int b = blk >> 10;
  const int sq = qt * 8 + rs;
  const int jbase = half * 256 + g * 8;

  const float* qrow = q + (size_t)(b * Sc + sq) * Ec + h * Dc;
  float4 qv[8];
#pragma unroll
  for (int i = 0; i < 8; ++i) qv[i] = ((const float4*)qrow)[i];
  const float q2 = qn[(b * Hc + h) * Sc + sq];
  const float q2x2 = q2 + q2;
  const float omq = 1.0f - q2;
  const float sinv = -1.0f / (hs[h] * sqrtf((float)Dc));

  const float* kbp = k + ((size_t)(b * Sc) + jbase) * Ec + h * Dc;
  const float* lvp = lv + ((size_t)(b * Sc) + jbase) * Ec + h * Dc;
  const float* knp = kn + (b * Hc + h) * Sc + jbase;

  float kk2[8];
#pragma unroll
  for (int i = 0; i < 8; ++i) kk2[i] = knp[i];

  float4 acc[8];
#pragma unroll
  for (int i = 0; i < 8; ++i) acc[i] = make_float4(0.f, 0.f, 0.f, 0.f);
  float l = 0.f;

#pragma unroll
  for (int jj = 0; jj < 8; ++jj) {
    const float4* kr = (const float4*)(kbp + (size_t)jj * Ec);
    const float4* lr = (const float4*)(lvp + (size_t)jj * Ec);
    float4 kv[8], lf[8];
#pragma unroll
    for (int i = 0; i < 8; ++i) kv[i] = kr[i];
#pragma unroll
    for (int i = 0; i < 8; ++i) lf[i] = lr[i];

    float kq = 0.f;
#pragma unroll
    for (int i = 0; i < 8; ++i) {
      kq = fmaf(qv[i].x, kv[i].x, kq);
      kq = fmaf(qv[i].y, kv[i].y, kq);
      kq = fmaf(qv[i].z, kv[i].z, kq);
      kq = fmaf(qv[i].w, kv[i].w, kq);
    }
    const float k2 = kk2[jj];
    const float omk = 1.0f - k2;
    float s2x2 = fmaf(-4.0f, kq, fmaf(2.0f, k2, q2x2));     // 2*||q-k||^2
    float dden = fmaf(k2, q2, fmaf(-2.0f, kq, 1.0f)) + 1e-15f;
    float P = fmaf(dden, omk * omq, 1e-20f);
    float rp = __builtin_amdgcn_rcpf(P);
    float tt = fmaxf(s2x2 * rp, 1e-7f);                     // a - 1
    float z = (1.0f + tt) + sqrtf(fmaf(tt, tt, tt + tt));   // a+sqrt(a^2-1)
    float p = __expf(sinv * __logf(z));
    l += p;
#pragma unroll
    for (int i = 0; i < 8; ++i) {
      acc[i].x = fmaf(p, lf[i].x, acc[i].x);
      acc[i].y = fmaf(p, lf[i].y, acc[i].y);
      acc[i].z = fmaf(p, lf[i].z, acc[i].z);
      acc[i].w = fmaf(p, lf[i].w, acc[i].w);
    }
  }

  // ---- merge 32 partials per row via half-size buffer (3 phases) ----
  __shared__ float accb[16][8][36];
  __shared__ float lsb[16][8];

  if (g >= 16) {
    float* ap = &accb[g - 16][rs][0];
#pragma unroll
    for (int i = 0; i < 8; ++i) ((float4*)ap)[i] = acc[i];
    lsb[g - 16][rs] = l;
  }
  __syncthreads();
  if (g < 16) {
    float* ap = &accb[g][rs][0];
#pragma unroll
    for (int i = 0; i < 8; ++i) {
      float4 t = ((float4*)ap)[i];
      t.x += acc[i].x; t.y += acc[i].y; t.z += acc[i].z; t.w += acc[i].w;
      ((float4*)ap)[i] = t;
    }
    lsb[g][rs] += l;
  }
  __syncthreads();

  // reduce 16 slots: thread (mr, md) handles row mr, dim md; write raw sums
  const int mr = tid >> 5;   // 0..7
  const int md = tid & 31;   // 0..31
  float osum = 0.f, lsum = 0.f;
#pragma unroll
  for (int gg = 0; gg < 16; ++gg) {
    osum += accb[gg][mr][md];
    lsum += lsb[gg][mr];
  }
  const int grow = (b * Hc + h) * Sc + qt * 8 + mr;
  pacc[((size_t)half * NROWS + grow) * Dc + md] = osum;
  if (md == 0) pls[half * NROWS + grow] = lsum;
}

// ---------------------------------------------------------------------------
// Merge the 2 j-halves, normalize, expmap0, write attention output.
// grid 1024 (8 rows per block of 256): thread (mr,md)
// ---------------------------------------------------------------------------
__global__ __launch_bounds__(256) void attn_merge(
    const float* __restrict__ pacc, const float* __restrict__ pls,
    float* __restrict__ out) {
  const int tid = threadIdx.x;
  const int mr = tid >> 5;
  const int md = tid & 31;
  const int r = blockIdx.x * 8 + mr;   // (b*Hc+h)*Sc + s, 0..8191
  float a0 = pacc[(size_t)r * Dc + md];
  float a1 = pacc[((size_t)NROWS + r) * Dc + md];
  float lsum = pls[r] + pls[NROWS + r];
  float o = (a0 + a1) / lsum;
  float un2 = o * o;
#pragma unroll
  for (int m = 16; m >= 1; m >>= 1) un2 += __shfl_xor(un2, m, 32);
  float un = sqrtf(fmaxf(un2, 1e-15f));
  float f = tanh_fast(un) / un;        // expmap0 factor (SC = 1)
  const int b = r >> 12;
  const int h = (r >> 9) & 7;
  const int s = r & (Sc - 1);
  out[(size_t)(b * Sc + s) * Ec + h * Dc + md] = o * f;
}

// ---------------------------------------------------------------------------
// Per-row hyp_linear epilogue for the output projection (sums K-split partials)
// ---------------------------------------------------------------------------
__global__ __launch_bounds__(256) void proj_stats(
    const float* __restrict__ xin, const float* __restrict__ mx,
    const float* __restrict__ bo, float* __restrict__ out) {
  const int t = threadIdx.x;
  const int row = blockIdx.x;
  const size_t idx = (size_t)row * Ec + t;
  const float xv = xin[idx];
  float m = 0.f;
#pragma unroll
  for (int p = 0; p < KSPLIT; ++p) m += mx[idx + (size_t)p * NEc];
  const float bb = bo[t];
  float vals[4] = {xv * xv, m * m, m * bb, bb * bb};
  __shared__ float red[4][4];
  __shared__ float fin[4];
#pragma unroll
  for (int i = 0; i < 4; ++i) {
    float v = fullWaveSum(vals[i]);
    if ((t & 63) == 0) red[i][t >> 6] = v;
  }
  __syncthreads();
  if (t < 4) fin[t] = red[t][0] + red[t][1] + red[t][2] + red[t][3];
  __syncthreads();

  float x2 = fin[0], mx2 = fin[1], mxb = fin[2], b2 = fin[3];
  float xn = sqrtf(fmaxf(x2, 1e-15f));
  float mxn = sqrtf(fmaxf(mx2, 1e-15f));
  float scl = tanh_fast((mxn / xn) * atanh_fast(fminf(xn, MAXNORM))) / mxn;
  float mvv = scl * m;
  float X2 = scl * scl * mx2;
  float XY = scl * mxb;
  float numc = 1.0f + 2.0f * XY + b2;
  float den = 1.0f + 2.0f * XY + X2 * b2 + 1e-15f;
  out[idx] = (numc * mvv + (1.0f - X2) * bb) / den;
}

extern "C" void kernel_launch(void* const* d_in, const int* in_sizes, int n_in,
                              void* d_out, int out_size, void* d_ws, size_t ws_size,
                              hipStream_t stream) {
  (void)in_sizes; (void)n_in; (void)out_size; (void)ws_size;
  const float* x  = (const float*)d_in[0];
  const float* Wq = (const float*)d_in[1];
  const float* bq = (const float*)d_in[2];
  const float* Wk = (const float*)d_in[3];
  const float* bk = (const float*)d_in[4];
  const float* Wv = (const float*)d_in[5];
  const float* bv = (const float*)d_in[6];
  const float* Wo = (const float*)d_in[7];
  const float* bo = (const float*)d_in[8];
  const float* hs = (const float*)d_in[9];

  float* ws = (float*)d_ws;
  const int NE = NEc;            // 262144
  const int NH = NROWS;          // 8192
  float* mxq = ws;               // KSPLIT*NE partials each
  float* mxk = mxq + KSPLIT * NE;
  float* mxv = mxk + KSPLIT * NE;
  float* mxo = mxv + KSPLIT * NE;
  float* qb  = mxo + KSPLIT * NE;
  float* kb  = qb + NE;
  float* lvb = kb + NE;
  float* aob = lvb + NE;
  float* qnb = aob + NE;
  float* knb = qnb + NH;
  float* pacc = knb + NH;        // 2 * NROWS * Dc
  float* pls  = pacc + 2 * NROWS * Dc;  // 2 * NROWS

  const int M = Bc * Sc;  // 1024 rows

  gemm_xwt<<<dim3(M / 32, 12, KSPLIT), 128, 0, stream>>>(x, Wq, Wk, Wv, mxq, mxk, mxv);
  qkv_stats<<<M, 256, 0, stream>>>(x, mxq, mxk, mxv, bq, bk, bv,
                                   qb, kb, lvb, qnb, knb);
  attn_kernel<<<2048, 256, 0, stream>>>(qb, kb, lvb, qnb, knb, hs, pacc, pls);
  attn_merge<<<NROWS / 8, 256, 0, stream>>>(pacc, pls, aob);
  gemm_xwt<<<dim3(M / 32, 4, KSPLIT), 128, 0, stream>>>(aob, Wo, Wo, Wo, mxo, mxo, mxo);
  proj_stats<<<M, 256, 0, stream>>>(aob, mxo, bo, (float*)d_out);
}

// Round 6
// 137.048 us; speedup vs baseline: 1.1051x; 1.1051x over previous
//
#include <hip/hip_runtime.h>
#include <math.h>

#define Ec 256
#define Sc 512
#define Bc 2
#define Hc 8
#define Dc 32
#define MAXNORM (1.0f - 1e-5f)
#define NEc (Bc * Sc * Ec)
#define KSPLIT 4
#define NROWS (Bc * Hc * Sc)   // 8192 (b,h,s) rows

__device__ __forceinline__ float fullWaveSum(float v) {
#pragma unroll
  for (int m = 32; m >= 1; m >>= 1) v += __shfl_xor(v, m, 64);
  return v;
}
__device__ __forceinline__ float halfWaveSum(float v) {
#pragma unroll
  for (int m = 16; m >= 1; m >>= 1) v += __shfl_xor(v, m, 64);
  return v;
}
__device__ __forceinline__ float atanh_fast(float z) {   // z in [0, 1)
  return 0.5f * __logf((1.0f + z) / (1.0f - z));
}
__device__ __forceinline__ float tanh_fast(float a) {    // a >= 0
  float e = __expf(-2.0f * a);
  return (1.0f - e) / (1.0f + e);
}

// ---------------------------------------------------------------------------
// Tiled GEMM partial: O[kz] = X[:, kz*64:(kz+1)*64] @ W[:, same]^T
// ---------------------------------------------------------------------------
__global__ __launch_bounds__(128) void gemm_xwt(
    const float* __restrict__ X,
    const float* __restrict__ W0, const float* __restrict__ W1,
    const float* __restrict__ W2,
    float* __restrict__ O0, float* __restrict__ O1, float* __restrict__ O2) {
  const int tid = threadIdx.x;
  const int bx = blockIdx.x;
  const int by = blockIdx.y;
  const int kz = blockIdx.z;
  const int mat = by >> 2;
  const int cb0 = (by & 3) * 64;
  const int rb0 = bx * 32;
  const int kk = kz * 64;
  const float* __restrict__ W = (mat == 0) ? W0 : (mat == 1) ? W1 : W2;
  float* __restrict__ O = ((mat == 0) ? O0 : (mat == 1) ? O1 : O2) + (size_t)kz * NEc;

  __shared__ float Xs[64][36];   // [k][row]
  __shared__ float Ws[64][68];   // [k][col]

  const int f4 = tid & 15;
  const int sub = tid >> 4;
  const int ty = tid >> 4;
  const int tx = tid & 15;

#pragma unroll
  for (int i = 0; i < 4; ++i) {
    int row = sub + i * 8;
    float4 v = *(const float4*)&X[(size_t)(rb0 + row) * Ec + kk + f4 * 4];
    Xs[f4 * 4 + 0][row] = v.x;
    Xs[f4 * 4 + 1][row] = v.y;
    Xs[f4 * 4 + 2][row] = v.z;
    Xs[f4 * 4 + 3][row] = v.w;
  }
#pragma unroll
  for (int i = 0; i < 8; ++i) {
    int col = sub + i * 8;
    float4 v = *(const float4*)&W[(size_t)(cb0 + col) * Ec + kk + f4 * 4];
    Ws[f4 * 4 + 0][col] = v.x;
    Ws[f4 * 4 + 1][col] = v.y;
    Ws[f4 * 4 + 2][col] = v.z;
    Ws[f4 * 4 + 3][col] = v.w;
  }
  __syncthreads();

  float acc[4][4];
#pragma unroll
  for (int i = 0; i < 4; ++i)
#pragma unroll
    for (int j = 0; j < 4; ++j) acc[i][j] = 0.f;

#pragma unroll 8
  for (int k = 0; k < 64; ++k) {
    float4 a = *(const float4*)&Xs[k][ty * 4];
    float4 b = *(const float4*)&Ws[k][tx * 4];
    float av[4] = {a.x, a.y, a.z, a.w};
    float bv[4] = {b.x, b.y, b.z, b.w};
#pragma unroll
    for (int i = 0; i < 4; ++i)
#pragma unroll
      for (int j = 0; j < 4; ++j) acc[i][j] = fmaf(av[i], bv[j], acc[i][j]);
  }
#pragma unroll
  for (int i = 0; i < 4; ++i) {
    float4 o = make_float4(acc[i][0], acc[i][1], acc[i][2], acc[i][3]);
    *(float4*)&O[(size_t)(rb0 + ty * 4 + i) * Ec + cb0 + tx * 4] = o;
  }
}

// ---------------------------------------------------------------------------
// Per-row hyp_linear epilogue for q/k/v (sums the 4 K-split partials)
// ---------------------------------------------------------------------------
__global__ __launch_bounds__(256) void qkv_stats(
    const float* __restrict__ x,
    const float* __restrict__ mxq, const float* __restrict__ mxk,
    const float* __restrict__ mxv,
    const float* __restrict__ bq, const float* __restrict__ bk,
    const float* __restrict__ bv,
    float* __restrict__ qo, float* __restrict__ ko, float* __restrict__ lvo,
    float* __restrict__ qno, float* __restrict__ kno) {
  const int t = threadIdx.x;
  const int row = blockIdx.x;
  const int b = row >> 9;
  const int s = row & (Sc - 1);
  const size_t idx = (size_t)row * Ec + t;
  const float xv = x[idx];
  float mq = 0.f, mk = 0.f, mv = 0.f;
#pragma unroll
  for (int p = 0; p < KSPLIT; ++p) {
    mq += mxq[idx + (size_t)p * NEc];
    mk += mxk[idx + (size_t)p * NEc];
    mv += mxv[idx + (size_t)p * NEc];
  }
  const float bb[3] = {bq[t], bk[t], bv[t]};
  const float mvals[3] = {mq, mk, mv};

  float vals[10] = {xv * xv,
                    mq * mq, mq * bb[0], bb[0] * bb[0],
                    mk * mk, mk * bb[1], bb[1] * bb[1],
                    mv * mv, mv * bb[2], bb[2] * bb[2]};
  __shared__ float red[10][4];
  __shared__ float fin[10];
#pragma unroll
  for (int i = 0; i < 10; ++i) {
    float v = fullWaveSum(vals[i]);
    if ((t & 63) == 0) red[i][t >> 6] = v;
  }
  __syncthreads();
  if (t < 10) fin[t] = red[t][0] + red[t][1] + red[t][2] + red[t][3];
  __syncthreads();

  const float x2 = fin[0];
  const float xn = sqrtf(fmaxf(x2, 1e-15f));
  const float at = atanh_fast(fminf(xn, MAXNORM));  // SC = 1
  const int h = t >> 5;

#pragma unroll
  for (int m = 0; m < 3; ++m) {
    float mx2 = fin[1 + 3 * m];
    float mxb = fin[2 + 3 * m];
    float b2 = fin[3 + 3 * m];
    float mxn = sqrtf(fmaxf(mx2, 1e-15f));
    float scl = tanh_fast((mxn / xn) * at) / mxn;
    float mvv = scl * mvals[m];
    float X2 = scl * scl * mx2;
    float XY = scl * mxb;
    float numc = 1.0f + 2.0f * XY + b2;
    float den = 1.0f + 2.0f * XY + X2 * b2 + 1e-15f;
    float res = (numc * mvv + (1.0f - X2) * bb[m]) / den;
    if (m < 2) {
      res = fminf(res, MAXNORM);                 // elementwise clamp_max
      float s2 = halfWaveSum(res * res);         // per-head ||.||^2 (C=1)
      if (m == 0) {
        qo[idx] = res;
        if ((t & 31) == 0) qno[(b * Hc + h) * Sc + s] = s2;
      } else {
        ko[idx] = res;
        if ((t & 31) == 0) kno[(b * Hc + h) * Sc + s] = s2;
      }
    } else {
      float vn2 = halfWaveSum(res * res);
      float vn = sqrtf(fmaxf(vn2, 1e-15f));
      float f = atanh_fast(fminf(vn, MAXNORM)) / vn;  // logmap0 factor
      lvo[idx] = f * res;
    }
  }
}

// ---------------------------------------------------------------------------
// Score kernel: P[bh][sq][sk] = exp(-acosh(a)/(hs*sqrt(D))) via Gram GEMM.
// 16 batched 512x512x32 GEMMs. grid (8 sk-tiles, 8 sq-tiles, 16 bh), blk 256.
// Tile 64x64; thread = (ty=row-group, tx=col-group) with 4x4 outputs.
// LDS [64][32] with float4-XOR swizzle (fd ^= (row>>2)&7) -> compute reads
// are <=2-way conflicts (free per m136).
// ---------------------------------------------------------------------------
__global__ __launch_bounds__(256) void score_kernel(
    const float* __restrict__ q, const float* __restrict__ k,
    const float* __restrict__ qn, const float* __restrict__ kn,
    const float* __restrict__ hs, float* __restrict__ P) {
  const int tid = threadIdx.x;
  const int sk0 = blockIdx.x * 64;
  const int sq0 = blockIdx.y * 64;
  const int bh = blockIdx.z;
  const int b = bh >> 3;
  const int h = bh & 7;

  __shared__ float Qs[64][32];
  __shared__ float Ks[64][32];

  // stage: 512 float4 per tile, 2 per thread
#pragma unroll
  for (int i = 0; i < 2; ++i) {
    int qi = tid + i * 256;
    int r = qi >> 3;
    int fd = qi & 7;
    int fsw = fd ^ ((r >> 2) & 7);
    float4 v = *(const float4*)&q[(size_t)(b * Sc + sq0 + r) * Ec + h * Dc + fd * 4];
    *(float4*)&Qs[r][fsw * 4] = v;
    float4 w = *(const float4*)&k[(size_t)(b * Sc + sk0 + r) * Ec + h * Dc + fd * 4];
    *(float4*)&Ks[r][fsw * 4] = w;
  }
  __syncthreads();

  const int ty = tid >> 4;
  const int tx = tid & 15;

  float acc[4][4];
#pragma unroll
  for (int i = 0; i < 4; ++i)
#pragma unroll
    for (int j = 0; j < 4; ++j) acc[i][j] = 0.f;

#pragma unroll
  for (int fd = 0; fd < 8; ++fd) {
    const int qsw = (fd ^ (ty & 7)) * 4;
    const int ksw = (fd ^ (tx & 7)) * 4;
    float4 a[4], bb[4];
#pragma unroll
    for (int i = 0; i < 4; ++i) a[i] = *(const float4*)&Qs[ty * 4 + i][qsw];
#pragma unroll
    for (int j = 0; j < 4; ++j) bb[j] = *(const float4*)&Ks[tx * 4 + j][ksw];
#pragma unroll
    for (int i = 0; i < 4; ++i)
#pragma unroll
      for (int j = 0; j < 4; ++j) {
        acc[i][j] = fmaf(a[i].x, bb[j].x, acc[i][j]);
        acc[i][j] = fmaf(a[i].y, bb[j].y, acc[i][j]);
        acc[i][j] = fmaf(a[i].z, bb[j].z, acc[i][j]);
        acc[i][j] = fmaf(a[i].w, bb[j].w, acc[i][j]);
      }
  }

  // epilogue: hyperbolic distance -> exp score
  const float sinv = -1.0f / (hs[h] * sqrtf((float)Dc));
  float qnv[4], knv[4];
#pragma unroll
  for (int i = 0; i < 4; ++i) qnv[i] = qn[bh * Sc + sq0 + ty * 4 + i];
#pragma unroll
  for (int j = 0; j < 4; ++j) knv[j] = kn[bh * Sc + sk0 + tx * 4 + j];

#pragma unroll
  for (int i = 0; i < 4; ++i) {
    const float q2 = qnv[i];
    const float omq = 1.0f - q2;
    float4 o;
    float po[4];
#pragma unroll
    for (int j = 0; j < 4; ++j) {
      const float k2 = knv[j];
      const float kq = acc[i][j];
      const float omk = 1.0f - k2;
      float s2x2 = fmaf(-4.0f, kq, 2.0f * k2 + 2.0f * q2);       // 2*||q-k||^2
      float dden = fmaf(k2, q2, fmaf(-2.0f, kq, 1.0f)) + 1e-15f;
      float Pd = fmaf(dden, omk * omq, 1e-20f);
      float rp = __builtin_amdgcn_rcpf(Pd);
      float tt = fmaxf(s2x2 * rp, 1e-7f);                        // a-1
      float z = (1.0f + tt) + sqrtf(fmaf(tt, tt, tt + tt));
      po[j] = __expf(sinv * __logf(z));
    }
    o.x = po[0]; o.y = po[1]; o.z = po[2]; o.w = po[3];
    *(float4*)&P[((size_t)bh * Sc + sq0 + ty * 4 + i) * Sc + sk0 + tx * 4] = o;
  }
}

// ---------------------------------------------------------------------------
// PV kernel: out = expmap0( (P @ LV) / rowsum(P) ).
// grid (16 sq-tiles of 32 rows, 16 bh), block 256: r = tid>>3, dq = tid&7.
// LDS-staged P-tile [32][64] (pad 68) and LV-tile [64][32] (pad 36);
// compute reads are broadcast (free). Row-sum comes free with the P reads.
// ---------------------------------------------------------------------------
__global__ __launch_bounds__(256) void pv_kernel(
    const float* __restrict__ P, const float* __restrict__ lv,
    float* __restrict__ out) {
  const int tid = threadIdx.x;
  const int sq0 = blockIdx.x * 32;
  const int bh = blockIdx.y;
  const int b = bh >> 3;
  const int h = bh & 7;
  const int r = tid >> 3;
  const int dq = tid & 7;

  __shared__ float Ps[32][68];
  __shared__ float lvs[64][36];

  float4 acc = make_float4(0.f, 0.f, 0.f, 0.f);
  float lsum = 0.f;

#pragma unroll 1
  for (int t = 0; t < 8; ++t) {
    const int j0 = t * 64;
#pragma unroll
    for (int i = 0; i < 2; ++i) {
      int qi = tid + i * 256;
      int pr = qi >> 4, pc = qi & 15;
      *(float4*)&Ps[pr][pc * 4] =
          *(const float4*)&P[((size_t)bh * Sc + sq0 + pr) * Sc + j0 + pc * 4];
      int lr = qi >> 3, lc = qi & 7;
      *(float4*)&lvs[lr][lc * 4] =
          *(const float4*)&lv[(size_t)(b * Sc + j0 + lr) * Ec + h * Dc + lc * 4];
    }
    __syncthreads();

#pragma unroll
    for (int j4 = 0; j4 < 16; ++j4) {
      float4 pv = *(const float4*)&Ps[r][j4 * 4];
      float4 l0 = *(const float4*)&lvs[j4 * 4 + 0][dq * 4];
      float4 l1 = *(const float4*)&lvs[j4 * 4 + 1][dq * 4];
      float4 l2 = *(const float4*)&lvs[j4 * 4 + 2][dq * 4];
      float4 l3 = *(const float4*)&lvs[j4 * 4 + 3][dq * 4];
      acc.x = fmaf(pv.x, l0.x, acc.x); acc.y = fmaf(pv.x, l0.y, acc.y);
      acc.z = fmaf(pv.x, l0.z, acc.z); acc.w = fmaf(pv.x, l0.w, acc.w);
      acc.x = fmaf(pv.y, l1.x, acc.x); acc.y = fmaf(pv.y, l1.y, acc.y);
      acc.z = fmaf(pv.y, l1.z, acc.z); acc.w = fmaf(pv.y, l1.w, acc.w);
      acc.x = fmaf(pv.z, l2.x, acc.x); acc.y = fmaf(pv.z, l2.y, acc.y);
      acc.z = fmaf(pv.z, l2.z, acc.z); acc.w = fmaf(pv.z, l2.w, acc.w);
      acc.x = fmaf(pv.w, l3.x, acc.x); acc.y = fmaf(pv.w, l3.y, acc.y);
      acc.z = fmaf(pv.w, l3.z, acc.z); acc.w = fmaf(pv.w, l3.w, acc.w);
      lsum += pv.x + pv.y + pv.z + pv.w;
    }
    __syncthreads();
  }

  const float li = 1.0f / lsum;
  float o[4] = {acc.x * li, acc.y * li, acc.z * li, acc.w * li};
  float un2 = fmaf(o[0], o[0], fmaf(o[1], o[1], fmaf(o[2], o[2], o[3] * o[3])));
#pragma unroll
  for (int m = 4; m >= 1; m >>= 1) un2 += __shfl_xor(un2, m, 8);
  float un = sqrtf(fmaxf(un2, 1e-15f));
  float f = tanh_fast(un) / un;       // expmap0 factor (SC = 1)
  float4 ov = make_float4(o[0] * f, o[1] * f, o[2] * f, o[3] * f);
  *(float4*)&out[(size_t)(b * Sc + sq0 + r) * Ec + h * Dc + dq * 4] = ov;
}

// ---------------------------------------------------------------------------
// Per-row hyp_linear epilogue for the output projection (sums K-split partials)
// ---------------------------------------------------------------------------
__global__ __launch_bounds__(256) void proj_stats(
    const float* __restrict__ xin, const float* __restrict__ mx,
    const float* __restrict__ bo, float* __restrict__ out) {
  const int t = threadIdx.x;
  const int row = blockIdx.x;
  const size_t idx = (size_t)row * Ec + t;
  const float xv = xin[idx];
  float m = 0.f;
#pragma unroll
  for (int p = 0; p < KSPLIT; ++p) m += mx[idx + (size_t)p * NEc];
  const float bb = bo[t];
  float vals[4] = {xv * xv, m * m, m * bb, bb * bb};
  __shared__ float red[4][4];
  __shared__ float fin[4];
#pragma unroll
  for (int i = 0; i < 4; ++i) {
    float v = fullWaveSum(vals[i]);
    if ((t & 63) == 0) red[i][t >> 6] = v;
  }
  __syncthreads();
  if (t < 4) fin[t] = red[t][0] + red[t][1] + red[t][2] + red[t][3];
  __syncthreads();

  float x2 = fin[0], mx2 = fin[1], mxb = fin[2], b2 = fin[3];
  float xn = sqrtf(fmaxf(x2, 1e-15f));
  float mxn = sqrtf(fmaxf(mx2, 1e-15f));
  float scl = tanh_fast((mxn / xn) * atanh_fast(fminf(xn, MAXNORM))) / mxn;
  float mvv = scl * m;
  float X2 = scl * scl * mx2;
  float XY = scl * mxb;
  float numc = 1.0f + 2.0f * XY + b2;
  float den = 1.0f + 2.0f * XY + X2 * b2 + 1e-15f;
  out[idx] = (numc * mvv + (1.0f - X2) * bb) / den;
}

extern "C" void kernel_launch(void* const* d_in, const int* in_sizes, int n_in,
                              void* d_out, int out_size, void* d_ws, size_t ws_size,
                              hipStream_t stream) {
  (void)in_sizes; (void)n_in; (void)out_size; (void)ws_size;
  const float* x  = (const float*)d_in[0];
  const float* Wq = (const float*)d_in[1];
  const float* bq = (const float*)d_in[2];
  const float* Wk = (const float*)d_in[3];
  const float* bk = (const float*)d_in[4];
  const float* Wv = (const float*)d_in[5];
  const float* bv = (const float*)d_in[6];
  const float* Wo = (const float*)d_in[7];
  const float* bo = (const float*)d_in[8];
  const float* hs = (const float*)d_in[9];

  float* ws = (float*)d_ws;
  const int NE = NEc;            // 262144
  const int NH = NROWS;          // 8192
  float* mxq = ws;               // KSPLIT*NE partials each
  float* mxk = mxq + KSPLIT * NE;
  float* mxv = mxk + KSPLIT * NE;
  float* mxo = mxv + KSPLIT * NE;
  float* qb  = mxo + KSPLIT * NE;
  float* kb  = qb + NE;
  float* lvb = kb + NE;
  float* aob = lvb + NE;
  float* qnb = aob + NE;
  float* knb = qnb + NH;
  float* Pb  = knb + NH;         // 16 * 512 * 512 = 4.19M floats (16.8 MB)

  const int M = Bc * Sc;  // 1024 rows

  gemm_xwt<<<dim3(M / 32, 12, KSPLIT), 128, 0, stream>>>(x, Wq, Wk, Wv, mxq, mxk, mxv);
  qkv_stats<<<M, 256, 0, stream>>>(x, mxq, mxk, mxv, bq, bk, bv,
                                   qb, kb, lvb, qnb, knb);
  score_kernel<<<dim3(8, 8, 16), 256, 0, stream>>>(qb, kb, qnb, knb, hs, Pb);
  pv_kernel<<<dim3(16, 16), 256, 0, stream>>>(Pb, lvb, aob);
  gemm_xwt<<<dim3(M / 32, 4, KSPLIT), 128, 0, stream>>>(aob, Wo, Wo, Wo, mxo, mxo, mxo);
  proj_stats<<<M, 256, 0, stream>>>(aob, mxo, bo, (float*)d_out);
}

// Round 8
// 125.041 us; speedup vs baseline: 1.2112x; 1.0960x over previous
//
#include <hip/hip_runtime.h>
#include <math.h>

#define Ec 256
#define Sc 512
#define Bc 2
#define Hc 8
#define Dc 32
#define MAXNORM (1.0f - 1e-5f)
#define NEc (Bc * Sc * Ec)
#define KSPLIT 4
#define NROWS (Bc * Hc * Sc)   // 8192 (b,h,s) rows

__device__ __forceinline__ float fullWaveSum(float v) {
#pragma unroll
  for (int m = 32; m >= 1; m >>= 1) v += __shfl_xor(v, m, 64);
  return v;
}
__device__ __forceinline__ float halfWaveSum(float v) {
#pragma unroll
  for (int m = 16; m >= 1; m >>= 1) v += __shfl_xor(v, m, 64);
  return v;
}
__device__ __forceinline__ float atanh_fast(float z) {   // z in [0, 1)
  return 0.5f * __logf((1.0f + z) / (1.0f - z));
}
__device__ __forceinline__ float tanh_fast(float a) {    // a >= 0
  float e = __expf(-2.0f * a);
  return (1.0f - e) / (1.0f + e);
}

// ---------------------------------------------------------------------------
// Tiled GEMM partial: O[kz] = X[:, kz*64:(kz+1)*64] @ W[:, same]^T
// ---------------------------------------------------------------------------
__global__ __launch_bounds__(128) void gemm_xwt(
    const float* __restrict__ X,
    const float* __restrict__ W0, const float* __restrict__ W1,
    const float* __restrict__ W2,
    float* __restrict__ O0, float* __restrict__ O1, float* __restrict__ O2) {
  const int tid = threadIdx.x;
  const int bx = blockIdx.x;
  const int by = blockIdx.y;
  const int kz = blockIdx.z;
  const int mat = by >> 2;
  const int cb0 = (by & 3) * 64;
  const int rb0 = bx * 32;
  const int kk = kz * 64;
  const float* __restrict__ W = (mat == 0) ? W0 : (mat == 1) ? W1 : W2;
  float* __restrict__ O = ((mat == 0) ? O0 : (mat == 1) ? O1 : O2) + (size_t)kz * NEc;

  __shared__ float Xs[64][36];   // [k][row]
  __shared__ float Ws[64][68];   // [k][col]

  const int f4 = tid & 15;
  const int sub = tid >> 4;
  const int ty = tid >> 4;
  const int tx = tid & 15;

#pragma unroll
  for (int i = 0; i < 4; ++i) {
    int row = sub + i * 8;
    float4 v = *(const float4*)&X[(size_t)(rb0 + row) * Ec + kk + f4 * 4];
    Xs[f4 * 4 + 0][row] = v.x;
    Xs[f4 * 4 + 1][row] = v.y;
    Xs[f4 * 4 + 2][row] = v.z;
    Xs[f4 * 4 + 3][row] = v.w;
  }
#pragma unroll
  for (int i = 0; i < 8; ++i) {
    int col = sub + i * 8;
    float4 v = *(const float4*)&W[(size_t)(cb0 + col) * Ec + kk + f4 * 4];
    Ws[f4 * 4 + 0][col] = v.x;
    Ws[f4 * 4 + 1][col] = v.y;
    Ws[f4 * 4 + 2][col] = v.z;
    Ws[f4 * 4 + 3][col] = v.w;
  }
  __syncthreads();

  float acc[4][4];
#pragma unroll
  for (int i = 0; i < 4; ++i)
#pragma unroll
    for (int j = 0; j < 4; ++j) acc[i][j] = 0.f;

#pragma unroll 8
  for (int k = 0; k < 64; ++k) {
    float4 a = *(const float4*)&Xs[k][ty * 4];
    float4 b = *(const float4*)&Ws[k][tx * 4];
    float av[4] = {a.x, a.y, a.z, a.w};
    float bv[4] = {b.x, b.y, b.z, b.w};
#pragma unroll
    for (int i = 0; i < 4; ++i)
#pragma unroll
      for (int j = 0; j < 4; ++j) acc[i][j] = fmaf(av[i], bv[j], acc[i][j]);
  }
#pragma unroll
  for (int i = 0; i < 4; ++i) {
    float4 o = make_float4(acc[i][0], acc[i][1], acc[i][2], acc[i][3]);
    *(float4*)&O[(size_t)(rb0 + ty * 4 + i) * Ec + cb0 + tx * 4] = o;
  }
}

// ---------------------------------------------------------------------------
// Per-row hyp_linear epilogue for q/k/v (sums the 4 K-split partials)
// ---------------------------------------------------------------------------
__global__ __launch_bounds__(256) void qkv_stats(
    const float* __restrict__ x,
    const float* __restrict__ mxq, const float* __restrict__ mxk,
    const float* __restrict__ mxv,
    const float* __restrict__ bq, const float* __restrict__ bk,
    const float* __restrict__ bv,
    float* __restrict__ qo, float* __restrict__ ko, float* __restrict__ lvo,
    float* __restrict__ qno, float* __restrict__ kno) {
  const int t = threadIdx.x;
  const int row = blockIdx.x;
  const int b = row >> 9;
  const int s = row & (Sc - 1);
  const size_t idx = (size_t)row * Ec + t;
  const float xv = x[idx];
  float mq = 0.f, mk = 0.f, mv = 0.f;
#pragma unroll
  for (int p = 0; p < KSPLIT; ++p) {
    mq += mxq[idx + (size_t)p * NEc];
    mk += mxk[idx + (size_t)p * NEc];
    mv += mxv[idx + (size_t)p * NEc];
  }
  const float bb[3] = {bq[t], bk[t], bv[t]};
  const float mvals[3] = {mq, mk, mv};

  float vals[10] = {xv * xv,
                    mq * mq, mq * bb[0], bb[0] * bb[0],
                    mk * mk, mk * bb[1], bb[1] * bb[1],
                    mv * mv, mv * bb[2], bb[2] * bb[2]};
  __shared__ float red[10][4];
  __shared__ float fin[10];
#pragma unroll
  for (int i = 0; i < 10; ++i) {
    float v = fullWaveSum(vals[i]);
    if ((t & 63) == 0) red[i][t >> 6] = v;
  }
  __syncthreads();
  if (t < 10) fin[t] = red[t][0] + red[t][1] + red[t][2] + red[t][3];
  __syncthreads();

  const float x2 = fin[0];
  const float xn = sqrtf(fmaxf(x2, 1e-15f));
  const float at = atanh_fast(fminf(xn, MAXNORM));  // SC = 1
  const int h = t >> 5;

#pragma unroll
  for (int m = 0; m < 3; ++m) {
    float mx2 = fin[1 + 3 * m];
    float mxb = fin[2 + 3 * m];
    float b2 = fin[3 + 3 * m];
    float mxn = sqrtf(fmaxf(mx2, 1e-15f));
    float scl = tanh_fast((mxn / xn) * at) / mxn;
    float mvv = scl * mvals[m];
    float X2 = scl * scl * mx2;
    float XY = scl * mxb;
    float numc = 1.0f + 2.0f * XY + b2;
    float den = 1.0f + 2.0f * XY + X2 * b2 + 1e-15f;
    float res = (numc * mvv + (1.0f - X2) * bb[m]) / den;
    if (m < 2) {
      res = fminf(res, MAXNORM);                 // elementwise clamp_max
      float s2 = halfWaveSum(res * res);         // per-head ||.||^2 (C=1)
      if (m == 0) {
        qo[idx] = res;
        if ((t & 31) == 0) qno[(b * Hc + h) * Sc + s] = s2;
      } else {
        ko[idx] = res;
        if ((t & 31) == 0) kno[(b * Hc + h) * Sc + s] = s2;
      }
    } else {
      float vn2 = halfWaveSum(res * res);
      float vn = sqrtf(fmaxf(vn2, 1e-15f));
      float f = atanh_fast(fminf(vn, MAXNORM)) / vn;  // logmap0 factor
      lvo[idx] = f * res;
    }
  }
}

// ---------------------------------------------------------------------------
// Score kernel: P[bh][sq][sk] = z^sinv, z = a + sqrt(a^2-1), via native
// v_log_f32 (log2) + v_exp_f32 (2^x) builtins.
// 16 batched 512x512x32 GEMMs. grid (8 sk-tiles, 8 sq-tiles, 16 bh), blk 256.
// ---------------------------------------------------------------------------
__global__ __launch_bounds__(256) void score_kernel(
    const float* __restrict__ q, const float* __restrict__ k,
    const float* __restrict__ qn, const float* __restrict__ kn,
    const float* __restrict__ hs, float* __restrict__ P) {
  const int tid = threadIdx.x;
  const int sk0 = blockIdx.x * 64;
  const int sq0 = blockIdx.y * 64;
  const int bh = blockIdx.z;
  const int b = bh >> 3;
  const int h = bh & 7;

  __shared__ float Qs[64][32];
  __shared__ float Ks[64][32];

#pragma unroll
  for (int i = 0; i < 2; ++i) {
    int qi = tid + i * 256;
    int r = qi >> 3;
    int fd = qi & 7;
    int fsw = fd ^ ((r >> 2) & 7);
    float4 v = *(const float4*)&q[(size_t)(b * Sc + sq0 + r) * Ec + h * Dc + fd * 4];
    *(float4*)&Qs[r][fsw * 4] = v;
    float4 w = *(const float4*)&k[(size_t)(b * Sc + sk0 + r) * Ec + h * Dc + fd * 4];
    *(float4*)&Ks[r][fsw * 4] = w;
  }
  __syncthreads();

  const int ty = tid >> 4;
  const int tx = tid & 15;

  float acc[4][4];
#pragma unroll
  for (int i = 0; i < 4; ++i)
#pragma unroll
    for (int j = 0; j < 4; ++j) acc[i][j] = 0.f;

#pragma unroll
  for (int fd = 0; fd < 8; ++fd) {
    const int qsw = (fd ^ (ty & 7)) * 4;
    const int ksw = (fd ^ (tx & 7)) * 4;
    float4 a[4], bb[4];
#pragma unroll
    for (int i = 0; i < 4; ++i) a[i] = *(const float4*)&Qs[ty * 4 + i][qsw];
#pragma unroll
    for (int j = 0; j < 4; ++j) bb[j] = *(const float4*)&Ks[tx * 4 + j][ksw];
#pragma unroll
    for (int i = 0; i < 4; ++i)
#pragma unroll
      for (int j = 0; j < 4; ++j) {
        acc[i][j] = fmaf(a[i].x, bb[j].x, acc[i][j]);
        acc[i][j] = fmaf(a[i].y, bb[j].y, acc[i][j]);
        acc[i][j] = fmaf(a[i].z, bb[j].z, acc[i][j]);
        acc[i][j] = fmaf(a[i].w, bb[j].w, acc[i][j]);
      }
  }

  // epilogue: hyperbolic distance -> p = z^sinv via native log2/exp2
  const float sinv = -1.0f / (hs[h] * sqrtf((float)Dc));
  float qnv[4], knv[4];
#pragma unroll
  for (int i = 0; i < 4; ++i) qnv[i] = qn[bh * Sc + sq0 + ty * 4 + i];
#pragma unroll
  for (int j = 0; j < 4; ++j) knv[j] = kn[bh * Sc + sk0 + tx * 4 + j];

#pragma unroll
  for (int i = 0; i < 4; ++i) {
    const float q2 = qnv[i];
    const float omq = 1.0f - q2;
    float4 o;
    float po[4];
#pragma unroll
    for (int j = 0; j < 4; ++j) {
      const float k2 = knv[j];
      const float kq = acc[i][j];
      const float omk = 1.0f - k2;
      float s2x2 = fmaf(-4.0f, kq, 2.0f * k2 + 2.0f * q2);       // 2*||q-k||^2
      float dden = fmaf(k2, q2, fmaf(-2.0f, kq, 1.0f)) + 1e-15f;
      float Pd = fmaf(dden, omk * omq, 1e-20f);
      float rp = __builtin_amdgcn_rcpf(Pd);
      float tt = fmaxf(s2x2 * rp, 1e-7f);                        // a-1
      float z = (1.0f + tt) + sqrtf(fmaf(tt, tt, tt + tt));
      // z^sinv = exp2(sinv * log2(z)) on v_log_f32 / v_exp_f32
      po[j] = __builtin_amdgcn_exp2f(sinv * __builtin_amdgcn_logf(z));
    }
    o.x = po[0]; o.y = po[1]; o.z = po[2]; o.w = po[3];
    *(float4*)&P[((size_t)bh * Sc + sq0 + ty * 4 + i) * Sc + sk0 + tx * 4] = o;
  }
}

// ---------------------------------------------------------------------------
// PV kernel v2: out = expmap0( (P @ LV) / rowsum(P) ).
// grid (32 sq-tiles of 16 rows, 16 bh) = 512 blocks, block 256:
//   js = tid>>5 (8 j-slices), rg = (tid>>3)&3 (4 row-quads), dq = tid&7 (4 d)
// Thread tile 4 rows x 4 dims x (8 j per 64-tile) -> 8 LDS b128 per 64 FMA
// (2.5x less LDS BW than v1; LDS-BW was v1's bound). js-partials merged via
// LDS. All compute reads verified <=2-way bank conflicts (free).
// ---------------------------------------------------------------------------
__global__ __launch_bounds__(256) void pv_kernel(
    const float* __restrict__ P, const float* __restrict__ lv,
    float* __restrict__ out) {
  const int tid = threadIdx.x;
  const int sq0 = blockIdx.x * 16;
  const int bh = blockIdx.y;
  const int b = bh >> 3;
  const int h = bh & 7;
  const int js = tid >> 5;
  const int rg = (tid >> 3) & 3;
  const int dq = tid & 7;

  __shared__ float Ps[16][68];
  __shared__ float lvs[64][36];
  __shared__ float accm[16][8][32];   // [row][js][d]
  __shared__ float lsb[16][9];

  float4 acc[4];
#pragma unroll
  for (int i = 0; i < 4; ++i) acc[i] = make_float4(0.f, 0.f, 0.f, 0.f);
  float lsum4[4] = {0.f, 0.f, 0.f, 0.f};

#pragma unroll 1
  for (int t = 0; t < 8; ++t) {
    const int j0g = t * 64;
    {
      int pr = tid >> 4, pc = tid & 15;
      *(float4*)&Ps[pr][pc * 4] =
          *(const float4*)&P[((size_t)bh * Sc + sq0 + pr) * Sc + j0g + pc * 4];
#pragma unroll
      for (int i = 0; i < 2; ++i) {
        int qi = tid + i * 256;
        int lr = qi >> 3, lc = qi & 7;
        *(float4*)&lvs[lr][lc * 4] =
            *(const float4*)&lv[(size_t)(b * Sc + j0g + lr) * Ec + h * Dc + lc * 4];
      }
    }
    __syncthreads();

#pragma unroll
    for (int j4 = 0; j4 < 2; ++j4) {
      const int j0 = js * 8 + j4 * 4;
      float4 p[4], l[4];
#pragma unroll
      for (int i = 0; i < 4; ++i) p[i] = *(const float4*)&Ps[rg * 4 + i][j0];
#pragma unroll
      for (int c = 0; c < 4; ++c) l[c] = *(const float4*)&lvs[j0 + c][dq * 4];
#pragma unroll
      for (int i = 0; i < 4; ++i) {
        lsum4[i] += (p[i].x + p[i].y) + (p[i].z + p[i].w);
        acc[i].x = fmaf(p[i].x, l[0].x, acc[i].x);
        acc[i].y = fmaf(p[i].x, l[0].y, acc[i].y);
        acc[i].z = fmaf(p[i].x, l[0].z, acc[i].z);
        acc[i].w = fmaf(p[i].x, l[0].w, acc[i].w);
        acc[i].x = fmaf(p[i].y, l[1].x, acc[i].x);
        acc[i].y = fmaf(p[i].y, l[1].y, acc[i].y);
        acc[i].z = fmaf(p[i].y, l[1].z, acc[i].z);
        acc[i].w = fmaf(p[i].y, l[1].w, acc[i].w);
        acc[i].x = fmaf(p[i].z, l[2].x, acc[i].x);
        acc[i].y = fmaf(p[i].z, l[2].y, acc[i].y);
        acc[i].z = fmaf(p[i].z, l[2].z, acc[i].z);
        acc[i].w = fmaf(p[i].z, l[2].w, acc[i].w);
        acc[i].x = fmaf(p[i].w, l[3].x, acc[i].x);
        acc[i].y = fmaf(p[i].w, l[3].y, acc[i].y);
        acc[i].z = fmaf(p[i].w, l[3].z, acc[i].z);
        acc[i].w = fmaf(p[i].w, l[3].w, acc[i].w);
      }
    }
    __syncthreads();
  }

  // merge js partials
#pragma unroll
  for (int i = 0; i < 4; ++i)
    *(float4*)&accm[rg * 4 + i][js][dq * 4] = acc[i];
  if (dq == 0) {
#pragma unroll
    for (int i = 0; i < 4; ++i) lsb[rg * 4 + i][js] = lsum4[i];
  }
  __syncthreads();

  const int r2 = tid >> 4;       // 0..15 (row)
  const int dd = tid & 15;       // 0..15, 2 dims each
  float o0 = 0.f, o1 = 0.f, ls = 0.f;
#pragma unroll
  for (int g = 0; g < 8; ++g) {
    float2 a2 = *(const float2*)&accm[r2][g][dd * 2];
    o0 += a2.x;
    o1 += a2.y;
    ls += lsb[r2][g];
  }
  const float li = 1.0f / ls;
  o0 *= li;
  o1 *= li;
  float un2 = fmaf(o0, o0, o1 * o1);
#pragma unroll
  for (int m = 8; m >= 1; m >>= 1) un2 += __shfl_xor(un2, m, 16);
  float un = sqrtf(fmaxf(un2, 1e-15f));
  float f = tanh_fast(un) / un;        // expmap0 factor (SC = 1)
  float2 ov = make_float2(o0 * f, o1 * f);
  *(float2*)&out[(size_t)(b * Sc + sq0 + r2) * Ec + h * Dc + dd * 2] = ov;
}

// ---------------------------------------------------------------------------
// Per-row hyp_linear epilogue for the output projection (sums K-split partials)
// ---------------------------------------------------------------------------
__global__ __launch_bounds__(256) void proj_stats(
    const float* __restrict__ xin, const float* __restrict__ mx,
    const float* __restrict__ bo, float* __restrict__ out) {
  const int t = threadIdx.x;
  const int row = blockIdx.x;
  const size_t idx = (size_t)row * Ec + t;
  const float xv = xin[idx];
  float m = 0.f;
#pragma unroll
  for (int p = 0; p < KSPLIT; ++p) m += mx[idx + (size_t)p * NEc];
  const float bb = bo[t];
  float vals[4] = {xv * xv, m * m, m * bb, bb * bb};
  __shared__ float red[4][4];
  __shared__ float fin[4];
#pragma unroll
  for (int i = 0; i < 4; ++i) {
    float v = fullWaveSum(vals[i]);
    if ((t & 63) == 0) red[i][t >> 6] = v;
  }
  __syncthreads();
  if (t < 4) fin[t] = red[t][0] + red[t][1] + red[t][2] + red[t][3];
  __syncthreads();

  float x2 = fin[0], mx2 = fin[1], mxb = fin[2], b2 = fin[3];
  float xn = sqrtf(fmaxf(x2, 1e-15f));
  float mxn = sqrtf(fmaxf(mx2, 1e-15f));
  float scl = tanh_fast((mxn / xn) * atanh_fast(fminf(xn, MAXNORM))) / mxn;
  float mvv = scl * m;
  float X2 = scl * scl * mx2;
  float XY = scl * mxb;
  float numc = 1.0f + 2.0f * XY + b2;
  float den = 1.0f + 2.0f * XY + X2 * b2 + 1e-15f;
  out[idx] = (numc * mvv + (1.0f - X2) * bb) / den;
}

extern "C" void kernel_launch(void* const* d_in, const int* in_sizes, int n_in,
                              void* d_out, int out_size, void* d_ws, size_t ws_size,
                              hipStream_t stream) {
  (void)in_sizes; (void)n_in; (void)out_size; (void)ws_size;
  const float* x  = (const float*)d_in[0];
  const float* Wq = (const float*)d_in[1];
  const float* bq = (const float*)d_in[2];
  const float* Wk = (const float*)d_in[3];
  const float* bk = (const float*)d_in[4];
  const float* Wv = (const float*)d_in[5];
  const float* bv = (const float*)d_in[6];
  const float* Wo = (const float*)d_in[7];
  const float* bo = (const float*)d_in[8];
  const float* hs = (const float*)d_in[9];

  float* ws = (float*)d_ws;
  const int NE = NEc;            // 262144
  const int NH = NROWS;          // 8192
  float* mxq = ws;               // KSPLIT*NE partials each
  float* mxk = mxq + KSPLIT * NE;
  float* mxv = mxk + KSPLIT * NE;
  float* mxo = mxv + KSPLIT * NE;
  float* qb  = mxo + KSPLIT * NE;
  float* kb  = qb + NE;
  float* lvb = kb + NE;
  float* aob = lvb + NE;
  float* qnb = aob + NE;
  float* knb = qnb + NH;
  float* Pb  = knb + NH;         // 16 * 512 * 512 floats (16.8 MB)

  const int M = Bc * Sc;  // 1024 rows

  gemm_xwt<<<dim3(M / 32, 12, KSPLIT), 128, 0, stream>>>(x, Wq, Wk, Wv, mxq, mxk, mxv);
  qkv_stats<<<M, 256, 0, stream>>>(x, mxq, mxk, mxv, bq, bk, bv,
                                   qb, kb, lvb, qnb, knb);
  score_kernel<<<dim3(8, 8, 16), 256, 0, stream>>>(qb, kb, qnb, knb, hs, Pb);
  pv_kernel<<<dim3(32, 16), 256, 0, stream>>>(Pb, lvb, aob);
  gemm_xwt<<<dim3(M / 32, 4, KSPLIT), 128, 0, stream>>>(aob, Wo, Wo, Wo, mxo, mxo, mxo);
  proj_stats<<<M, 256, 0, stream>>>(aob, mxo, bo, (float*)d_out);
}